// Round 1
// baseline (579.401 us; speedup 1.0000x reference)
//
#include <hip/hip_runtime.h>
#include <math.h>

#define LST 68   // LDS row stride (floats): 64 + 4 pad -> 272B rows, 16B aligned

__global__ __launch_bounds__(256, 2) void bigbird_attn(
    const float* __restrict__ Qg, const float* __restrict__ Kg, const float* __restrict__ Vg,
    const float* __restrict__ band_mask, const float* __restrict__ from_mask,
    const float* __restrict__ to_mask, const float* __restrict__ fbm,
    const float* __restrict__ tbm, const int* __restrict__ rand_attn,
    float* __restrict__ out)
{
    const int B = 2, H = 12, S = 4096;
    __shared__ float Qs[64*LST];
    __shared__ float Ks[64*LST];
    __shared__ float Vs[64*LST];
    __shared__ float Ps[64*LST];

    const int tid = threadIdx.x;
    const int tq = tid >> 4;      // 0..15 -> q rows tq+16i
    const int tk = tid & 15;      // 0..15 -> k cols tk+16j / dd = tk*4

    int wg = blockIdx.x;
    int b, h, m;
    if (wg < B*H*2) {                     // full rows first (load balance)
        b = wg / (H*2);
        int r = wg - b*H*2;
        h = r >> 1;
        m = (r & 1) ? 63 : 0;
    } else {
        int w = wg - B*H*2;
        b = w / (H*62);
        int r = w - b*H*62;
        h = r / 62;
        m = 1 + (r - h*62);
    }

    const long bh = (long)b*H + h;
    const float* Qb = Qg + (bh*S + (long)m*64)*64;
    const float* Kb = Kg + bh*S*64;
    const float* Vb = Vg + bh*S*64;

    const bool isFull = (m == 0) || (m == 63);
    const bool isMid  = (m >= 2) && (m <= 61);
    int nt;
    int r0 = 1, r1 = 1, r2 = 1;
    if (isFull) nt = 64;
    else {
        const int* ra = rand_attn + (bh*62 + (m-1))*3;
        r0 = ra[0]; r1 = ra[1]; r2 = ra[2];
        nt = isMid ? 8 : 7;
    }

    // stage Q block (64x64)
    #pragma unroll
    for (int c = 0; c < 4; ++c) {
        int s = tid + 256*c;
        int row = s >> 4, c4 = (s & 15) << 2;
        *(float4*)&Qs[row*LST + c4] = *(const float4*)&Qb[row*64 + c4];
    }

    float4 acc[4];
    float mrow[4], lrow[4];
    #pragma unroll
    for (int i = 0; i < 4; ++i) {
        acc[i] = make_float4(0.f, 0.f, 0.f, 0.f);
        mrow[i] = -INFINITY; lrow[i] = 0.f;
    }

    for (int t = 0; t < nt; ++t) {
        // tile t -> (key block, mask type). ty: 0=to_mask, 1..3=window(widx=ty-1), 4=rand
        int blk, ty;
        if (isFull)      { blk = t; ty = 0; }
        else if (isMid) {
            if (t == 0)      { blk = 0;       ty = 0; }
            else if (t <= 3) { blk = m-2 + t; ty = t; }
            else if (t <= 6) { blk = (t==4)?r0:((t==5)?r1:r2); ty = 4; }
            else             { blk = 63;      ty = 0; }
        } else { // m==1 or m==62
            if (t < 4) { blk = (m==1) ? ((t<3)? t : 63) : ((t==0)? 0 : 60+t); ty = 0; }
            else       { blk = (t==4)?r0:((t==5)?r1:r2); ty = 4; }
        }

        __syncthreads();   // previous tile's PV done -> safe to overwrite K/V/P
        {
            const float* Kt = Kb + (long)blk*64*64;
            const float* Vt = Vb + (long)blk*64*64;
            #pragma unroll
            for (int c = 0; c < 4; ++c) {
                int s = tid + 256*c;
                int row = s >> 4, c4 = (s & 15) << 2;
                *(float4*)&Ks[row*LST + c4] = *(const float4*)&Kt[row*64 + c4];
                *(float4*)&Vs[row*LST + c4] = *(const float4*)&Vt[row*64 + c4];
            }
        }
        __syncthreads();   // staging visible

        // ---- QK^T: 4q x 4k per thread ----
        float sv[4][4];
        #pragma unroll
        for (int i = 0; i < 4; ++i)
            #pragma unroll
            for (int j = 0; j < 4; ++j) sv[i][j] = 0.f;

        #pragma unroll 4
        for (int d0 = 0; d0 < 64; d0 += 4) {
            float4 qv[4], kv[4];
            #pragma unroll
            for (int i = 0; i < 4; ++i) qv[i] = *(const float4*)&Qs[(tq+16*i)*LST + d0];
            #pragma unroll
            for (int j = 0; j < 4; ++j) kv[j] = *(const float4*)&Ks[(tk+16*j)*LST + d0];
            #pragma unroll
            for (int i = 0; i < 4; ++i)
                #pragma unroll
                for (int j = 0; j < 4; ++j)
                    sv[i][j] += qv[i].x*kv[j].x + qv[i].y*kv[j].y
                              + qv[i].z*kv[j].z + qv[i].w*kv[j].w;
        }

        // ---- scale + mask addend ----
        float sres[4][4];
        if (ty == 0) {
            float ak[4];
            #pragma unroll
            for (int j = 0; j < 4; ++j)
                ak[j] = (1.f - to_mask[(long)b*S + blk*64 + tk + 16*j]) * -10000.f;
            #pragma unroll
            for (int i = 0; i < 4; ++i)
                #pragma unroll
                for (int j = 0; j < 4; ++j)
                    sres[i][j] = sv[i][j]*0.125f + ak[j];
        } else if (ty <= 3) {
            const float* bmb = band_mask + ((long)(b*60 + (m-2))*64)*192 + (ty-1)*64;
            #pragma unroll
            for (int i = 0; i < 4; ++i)
                #pragma unroll
                for (int j = 0; j < 4; ++j) {
                    float bm = bmb[(tq+16*i)*192 + tk + 16*j];
                    sres[i][j] = sv[i][j]*0.125f + (1.f - bm) * -10000.f;
                }
        } else {
            float fq[4], tb[4];
            #pragma unroll
            for (int i = 0; i < 4; ++i) fq[i] = fbm[((long)b*64 + m)*64 + tq + 16*i];
            #pragma unroll
            for (int j = 0; j < 4; ++j) tb[j] = tbm[((long)b*64 + blk)*64 + tk + 16*j];
            #pragma unroll
            for (int i = 0; i < 4; ++i)
                #pragma unroll
                for (int j = 0; j < 4; ++j)
                    sres[i][j] = sv[i][j]*0.125f + (1.f - fq[i]*tb[j]) * -10000.f;
        }

        // ---- online softmax (16 threads share a q row; butterfly over tk) ----
        #pragma unroll
        for (int i = 0; i < 4; ++i) {
            float tm = fmaxf(fmaxf(sres[i][0], sres[i][1]), fmaxf(sres[i][2], sres[i][3]));
            tm = fmaxf(tm, __shfl_xor(tm, 1));
            tm = fmaxf(tm, __shfl_xor(tm, 2));
            tm = fmaxf(tm, __shfl_xor(tm, 4));
            tm = fmaxf(tm, __shfl_xor(tm, 8));
            float mn = fmaxf(mrow[i], tm);
            float alpha = __expf(mrow[i] - mn);
            float p0 = __expf(sres[i][0] - mn);
            float p1 = __expf(sres[i][1] - mn);
            float p2 = __expf(sres[i][2] - mn);
            float p3 = __expf(sres[i][3] - mn);
            float ls = p0 + p1 + p2 + p3;
            ls += __shfl_xor(ls, 1);
            ls += __shfl_xor(ls, 2);
            ls += __shfl_xor(ls, 4);
            ls += __shfl_xor(ls, 8);
            lrow[i] = lrow[i]*alpha + ls;
            mrow[i] = mn;
            acc[i].x *= alpha; acc[i].y *= alpha; acc[i].z *= alpha; acc[i].w *= alpha;
            Ps[(tq+16*i)*LST + tk     ] = p0;
            Ps[(tq+16*i)*LST + tk + 16] = p1;
            Ps[(tq+16*i)*LST + tk + 32] = p2;
            Ps[(tq+16*i)*LST + tk + 48] = p3;
        }
        __syncthreads();   // P visible

        // ---- PV: 4q x 4dd per thread, dd = tk*4 ----
        #pragma unroll 4
        for (int k0 = 0; k0 < 64; k0 += 4) {
            float4 v0 = *(const float4*)&Vs[(k0+0)*LST + tk*4];
            float4 v1 = *(const float4*)&Vs[(k0+1)*LST + tk*4];
            float4 v2 = *(const float4*)&Vs[(k0+2)*LST + tk*4];
            float4 v3 = *(const float4*)&Vs[(k0+3)*LST + tk*4];
            #pragma unroll
            for (int i = 0; i < 4; ++i) {
                float4 pv = *(const float4*)&Ps[(tq+16*i)*LST + k0];
                acc[i].x += pv.x*v0.x + pv.y*v1.x + pv.z*v2.x + pv.w*v3.x;
                acc[i].y += pv.x*v0.y + pv.y*v1.y + pv.z*v2.y + pv.w*v3.y;
                acc[i].z += pv.x*v0.z + pv.y*v1.z + pv.z*v2.z + pv.w*v3.z;
                acc[i].w += pv.x*v0.w + pv.y*v1.w + pv.z*v2.w + pv.w*v3.w;
            }
        }
    }

    // ---- epilogue: normalize, from_mask, write (b, s, h, d) ----
    #pragma unroll
    for (int i = 0; i < 4; ++i) {
        int q = m*64 + tq + 16*i;
        float sc = (1.f / lrow[i]) * from_mask[(long)b*S + q];
        float4 o;
        o.x = acc[i].x * sc; o.y = acc[i].y * sc;
        o.z = acc[i].z * sc; o.w = acc[i].w * sc;
        *(float4*)&out[((long)((long)b*S + q)*H + h)*64 + tk*4] = o;
    }
}

extern "C" void kernel_launch(void* const* d_in, const int* in_sizes, int n_in,
                              void* d_out, int out_size, void* d_ws, size_t ws_size,
                              hipStream_t stream) {
    const float* q   = (const float*)d_in[0];
    const float* k   = (const float*)d_in[1];
    const float* v   = (const float*)d_in[2];
    const float* bm  = (const float*)d_in[3];
    const float* fm  = (const float*)d_in[4];
    const float* tm  = (const float*)d_in[5];
    const float* fbm = (const float*)d_in[6];
    const float* tbm = (const float*)d_in[7];
    const int*   ra  = (const int*)d_in[8];
    float* out = (float*)d_out;

    bigbird_attn<<<dim3(2*12*64), dim3(256), 0, stream>>>(q, k, v, bm, fm, tm, fbm, tbm, ra, out);
}

// Round 4
// 416.787 us; speedup vs baseline: 1.3902x; 1.3902x over previous
//
#include <hip/hip_runtime.h>
#include <math.h>

#define LST 68   // LDS row stride (floats): 64 + 4 pad -> 272B rows, 16B aligned
#define PS  4224 // partial stride (floats): 64*64 acc + 64 m + 64 l

__global__ __launch_bounds__(256, 2) void bigbird_attn(
    const float* __restrict__ Qg, const float* __restrict__ Kg, const float* __restrict__ Vg,
    const float* __restrict__ band_mask, const float* __restrict__ from_mask,
    const float* __restrict__ to_mask, const float* __restrict__ fbm,
    const float* __restrict__ tbm, const int* __restrict__ rand_attn,
    float* __restrict__ out, float* __restrict__ ws)
{
    const int B = 2, H = 12, S = 4096;
    __shared__ float Qs[64*LST];
    __shared__ float Ks[64*LST];
    __shared__ float Vs[64*LST];
    __shared__ float Ps[64*LST];

    const int tid = threadIdx.x;
    const int tq = tid >> 4;      // 0..15 -> q rows tq+16i
    const int tk = tid & 15;      // 0..15 -> k cols tk+16j / dd = tk*4

    int wg = blockIdx.x;
    int b, h, m, seg = 0;
    bool partial;
    if (wg < 384) {                      // full rows, split into 8 segments each
        partial = true;
        b = wg / 192;
        int r = wg - b*192;              // 0..191
        h = r >> 4;                      // 0..11
        int r2 = r & 15;
        m = (r2 >> 3) ? 63 : 0;
        seg = r2 & 7;
    } else {
        partial = false;
        int w = wg - 384;
        b = w / (H*62);
        int r = w - b*H*62;
        h = r / 62;
        m = 1 + (r - h*62);
    }

    const long bh = (long)b*H + h;
    const float* Qb = Qg + (bh*S + (long)m*64)*64;
    const float* Kb = Kg + bh*S*64;
    const float* Vb = Vg + bh*S*64;

    const bool isMid  = (m >= 2) && (m <= 61);
    int nt;
    int r0 = 1, r1 = 1, r2i = 1;
    if (partial) nt = 8;
    else {
        const int* ra = rand_attn + (bh*62 + (m-1))*3;
        r0 = ra[0]; r1 = ra[1]; r2i = ra[2];
        nt = isMid ? 8 : 7;
    }

    // stage Q block (64x64)
    #pragma unroll
    for (int c = 0; c < 4; ++c) {
        int s = tid + 256*c;
        int row = s >> 4, c4 = (s & 15) << 2;
        *(float4*)&Qs[row*LST + c4] = *(const float4*)&Qb[row*64 + c4];
    }

    float4 acc[4];
    float mrow[4], lrow[4];
    #pragma unroll
    for (int i = 0; i < 4; ++i) {
        acc[i] = make_float4(0.f, 0.f, 0.f, 0.f);
        mrow[i] = -INFINITY; lrow[i] = 0.f;
    }

    for (int t = 0; t < nt; ++t) {
        // tile t -> (key block, mask type). ty: 0=to_mask, 1..3=window(widx=ty-1), 4=rand
        int blk, ty;
        if (partial)     { blk = seg*8 + t; ty = 0; }
        else if (isMid) {
            if (t == 0)      { blk = 0;       ty = 0; }
            else if (t <= 3) { blk = m-2 + t; ty = t; }
            else if (t <= 6) { blk = (t==4)?r0:((t==5)?r1:r2i); ty = 4; }
            else             { blk = 63;      ty = 0; }
        } else { // m==1 or m==62
            if (t < 4) { blk = (m==1) ? ((t<3)? t : 63) : ((t==0)? 0 : 60+t); ty = 0; }
            else       { blk = (t==4)?r0:((t==5)?r1:r2i); ty = 4; }
        }

        __syncthreads();   // previous tile's PV done -> safe to overwrite K/V/P
        {
            const float* Kt = Kb + (long)blk*64*64;
            const float* Vt = Vb + (long)blk*64*64;
            #pragma unroll
            for (int c = 0; c < 4; ++c) {
                int s = tid + 256*c;
                int row = s >> 4, c4 = (s & 15) << 2;
                *(float4*)&Ks[row*LST + c4] = *(const float4*)&Kt[row*64 + c4];
                *(float4*)&Vs[row*LST + c4] = *(const float4*)&Vt[row*64 + c4];
            }
        }
        __syncthreads();   // staging visible

        // ---- QK^T: 4q x 4k per thread ----
        float sv[4][4];
        #pragma unroll
        for (int i = 0; i < 4; ++i)
            #pragma unroll
            for (int j = 0; j < 4; ++j) sv[i][j] = 0.f;

        #pragma unroll 4
        for (int d0 = 0; d0 < 64; d0 += 4) {
            float4 qv[4], kv[4];
            #pragma unroll
            for (int i = 0; i < 4; ++i) qv[i] = *(const float4*)&Qs[(tq+16*i)*LST + d0];
            #pragma unroll
            for (int j = 0; j < 4; ++j) kv[j] = *(const float4*)&Ks[(tk+16*j)*LST + d0];
            #pragma unroll
            for (int i = 0; i < 4; ++i)
                #pragma unroll
                for (int j = 0; j < 4; ++j)
                    sv[i][j] += qv[i].x*kv[j].x + qv[i].y*kv[j].y
                              + qv[i].z*kv[j].z + qv[i].w*kv[j].w;
        }

        // ---- scale + mask addend ----
        float sres[4][4];
        if (ty == 0) {
            float ak[4];
            #pragma unroll
            for (int j = 0; j < 4; ++j)
                ak[j] = (1.f - to_mask[(long)b*S + blk*64 + tk + 16*j]) * -10000.f;
            #pragma unroll
            for (int i = 0; i < 4; ++i)
                #pragma unroll
                for (int j = 0; j < 4; ++j)
                    sres[i][j] = sv[i][j]*0.125f + ak[j];
        } else if (ty <= 3) {
            const float* bmb = band_mask + ((long)(b*60 + (m-2))*64)*192 + (ty-1)*64;
            #pragma unroll
            for (int i = 0; i < 4; ++i)
                #pragma unroll
                for (int j = 0; j < 4; ++j) {
                    float bm = bmb[(tq+16*i)*192 + tk + 16*j];
                    sres[i][j] = sv[i][j]*0.125f + (1.f - bm) * -10000.f;
                }
        } else {
            float fq[4], tb[4];
            #pragma unroll
            for (int i = 0; i < 4; ++i) fq[i] = fbm[((long)b*64 + m)*64 + tq + 16*i];
            #pragma unroll
            for (int j = 0; j < 4; ++j) tb[j] = tbm[((long)b*64 + blk)*64 + tk + 16*j];
            #pragma unroll
            for (int i = 0; i < 4; ++i)
                #pragma unroll
                for (int j = 0; j < 4; ++j)
                    sres[i][j] = sv[i][j]*0.125f + (1.f - fq[i]*tb[j]) * -10000.f;
        }

        // ---- online softmax (16 threads share a q row; butterfly over tk) ----
        #pragma unroll
        for (int i = 0; i < 4; ++i) {
            float tm = fmaxf(fmaxf(sres[i][0], sres[i][1]), fmaxf(sres[i][2], sres[i][3]));
            tm = fmaxf(tm, __shfl_xor(tm, 1));
            tm = fmaxf(tm, __shfl_xor(tm, 2));
            tm = fmaxf(tm, __shfl_xor(tm, 4));
            tm = fmaxf(tm, __shfl_xor(tm, 8));
            float mn = fmaxf(mrow[i], tm);
            float alpha = __expf(mrow[i] - mn);
            float p0 = __expf(sres[i][0] - mn);
            float p1 = __expf(sres[i][1] - mn);
            float p2 = __expf(sres[i][2] - mn);
            float p3 = __expf(sres[i][3] - mn);
            float ls = p0 + p1 + p2 + p3;
            ls += __shfl_xor(ls, 1);
            ls += __shfl_xor(ls, 2);
            ls += __shfl_xor(ls, 4);
            ls += __shfl_xor(ls, 8);
            lrow[i] = lrow[i]*alpha + ls;
            mrow[i] = mn;
            acc[i].x *= alpha; acc[i].y *= alpha; acc[i].z *= alpha; acc[i].w *= alpha;
            Ps[(tq+16*i)*LST + tk     ] = p0;
            Ps[(tq+16*i)*LST + tk + 16] = p1;
            Ps[(tq+16*i)*LST + tk + 32] = p2;
            Ps[(tq+16*i)*LST + tk + 48] = p3;
        }
        __syncthreads();   // P visible

        // ---- PV: 4q x 4dd per thread, dd = tk*4 ----
        #pragma unroll 4
        for (int k0 = 0; k0 < 64; k0 += 4) {
            float4 v0 = *(const float4*)&Vs[(k0+0)*LST + tk*4];
            float4 v1 = *(const float4*)&Vs[(k0+1)*LST + tk*4];
            float4 v2 = *(const float4*)&Vs[(k0+2)*LST + tk*4];
            float4 v3 = *(const float4*)&Vs[(k0+3)*LST + tk*4];
            #pragma unroll
            for (int i = 0; i < 4; ++i) {
                float4 pv = *(const float4*)&Ps[(tq+16*i)*LST + k0];
                acc[i].x += pv.x*v0.x + pv.y*v1.x + pv.z*v2.x + pv.w*v3.x;
                acc[i].y += pv.x*v0.y + pv.y*v1.y + pv.z*v2.y + pv.w*v3.y;
                acc[i].z += pv.x*v0.z + pv.y*v1.z + pv.z*v2.z + pv.w*v3.z;
                acc[i].w += pv.x*v0.w + pv.y*v1.w + pv.z*v2.w + pv.w*v3.w;
            }
        }
    }

    if (partial) {
        // unnormalized partial: acc, m, l -> ws
        float* P = ws + ((((long)b*H + h)*2 + (m ? 1 : 0))*8 + seg) * PS;
        #pragma unroll
        for (int i = 0; i < 4; ++i) {
            int q = tq + 16*i;
            *(float4*)&P[q*64 + tk*4] = acc[i];
            if (tk == 0) { P[4096 + q] = mrow[i]; P[4160 + q] = lrow[i]; }
        }
    } else {
        // ---- epilogue: normalize, from_mask, write (b, s, h, d) ----
        #pragma unroll
        for (int i = 0; i < 4; ++i) {
            int q = m*64 + tq + 16*i;
            float sc = (1.f / lrow[i]) * from_mask[(long)b*S + q];
            float4 o;
            o.x = acc[i].x * sc; o.y = acc[i].y * sc;
            o.z = acc[i].z * sc; o.w = acc[i].w * sc;
            *(float4*)&out[((long)((long)b*S + q)*H + h)*64 + tk*4] = o;
        }
    }
}

__global__ __launch_bounds__(256) void bigbird_reduce(
    const float* __restrict__ ws, const float* __restrict__ from_mask,
    float* __restrict__ out)
{
    const int H = 12, S = 4096;
    int rowIdx = blockIdx.x;                 // 0..47 = (b*H + h)*2 + mi
    int b  = rowIdx / 24;
    int r  = rowIdx - b*24;
    int h  = r >> 1;
    int mi = r & 1;
    int m  = mi ? 63 : 0;

    const float* base = ws + (long)rowIdx * 8 * PS;
    int tid = threadIdx.x;
    int q  = tid >> 2;           // 0..63
    int dd = (tid & 3) << 4;     // 0,16,32,48

    float msg[8], lsg[8];
    float M = -INFINITY;
    #pragma unroll
    for (int s = 0; s < 8; ++s) {
        msg[s] = base[s*PS + 4096 + q];
        lsg[s] = base[s*PS + 4160 + q];
        M = fmaxf(M, msg[s]);
    }
    float L = 0.f, w[8];
    #pragma unroll
    for (int s = 0; s < 8; ++s) { w[s] = __expf(msg[s] - M); L += w[s]*lsg[s]; }

    int qg = m*64 + q;
    float sc = from_mask[(long)b*S + qg] / L;

    #pragma unroll
    for (int c = 0; c < 4; ++c) {
        float4 o = make_float4(0.f, 0.f, 0.f, 0.f);
        #pragma unroll
        for (int s = 0; s < 8; ++s) {
            float4 a = *(const float4*)&base[s*PS + q*64 + dd + 4*c];
            o.x += w[s]*a.x; o.y += w[s]*a.y; o.z += w[s]*a.z; o.w += w[s]*a.w;
        }
        o.x *= sc; o.y *= sc; o.z *= sc; o.w *= sc;
        *(float4*)&out[((long)((long)b*S + qg)*H + h)*64 + dd + 4*c] = o;
    }
}

extern "C" void kernel_launch(void* const* d_in, const int* in_sizes, int n_in,
                              void* d_out, int out_size, void* d_ws, size_t ws_size,
                              hipStream_t stream) {
    const float* q   = (const float*)d_in[0];
    const float* k   = (const float*)d_in[1];
    const float* v   = (const float*)d_in[2];
    const float* bm  = (const float*)d_in[3];
    const float* fm  = (const float*)d_in[4];
    const float* tm  = (const float*)d_in[5];
    const float* fbm = (const float*)d_in[6];
    const float* tbm = (const float*)d_in[7];
    const int*   ra  = (const int*)d_in[8];
    float* out = (float*)d_out;
    float* ws  = (float*)d_ws;   // 48 rows * 8 segs * 4224 floats = 6.5 MB

    bigbird_attn<<<dim3(384 + 2*12*62), dim3(256), 0, stream>>>(q, k, v, bm, fm, tm, fbm, tbm, ra, out, ws);
    bigbird_reduce<<<dim3(48), dim3(256), 0, stream>>>(ws, fm, out);
}

// Round 7
// 273.708 us; speedup vs baseline: 2.1169x; 1.5227x over previous
//
#include <hip/hip_runtime.h>
#include <math.h>

#define PS 4224          // partial stride (floats): 64*64 acc + 64 m + 64 l
#define LROW 72          // ushorts per LDS row: 64 + 8 pad = 144 B (16B-aligned, 9 bank-quads)

typedef short short8v __attribute__((ext_vector_type(8)));
typedef float f32x4  __attribute__((ext_vector_type(4)));

// LDS region offsets (ushort units)
#define QH  0
#define QL  (QH + 64*LROW)
#define KH  (QL + 64*LROW)
#define KL  (KH + 64*LROW)
#define VTH (KL + 64*LROW)
#define VTL (VTH + 64*LROW)
#define PHO (VTL + 64*LROW)
#define PLO (PHO + 64*LROW)
#define LDS_TOT (PLO + 64*LROW)   // 36864 ushorts = 73728 B -> 2 WG/CU

__device__ __forceinline__ unsigned au(float x){ return __float_as_uint(x); }
__device__ __forceinline__ float    af(unsigned x){ return __uint_as_float(x); }

// split 4 floats into packed-bf16 hi pair-words and lo pair-words (truncate; lo compensates exactly)
__device__ __forceinline__ void pack4(float a, float b, float c, float d,
                                      unsigned &h01, unsigned &h23,
                                      unsigned &l01, unsigned &l23) {
    unsigned u0=au(a), u1=au(b), u2=au(c), u3=au(d);
    h01 = __builtin_amdgcn_perm(u1, u0, 0x07060302);   // [u1.hi16 | u0.hi16]
    h23 = __builtin_amdgcn_perm(u3, u2, 0x07060302);
    float r0 = a - af(u0 & 0xffff0000u);
    float r1 = b - af(u1 & 0xffff0000u);
    float r2 = c - af(u2 & 0xffff0000u);
    float r3 = d - af(u3 & 0xffff0000u);
    l01 = __builtin_amdgcn_perm(au(r1), au(r0), 0x07060302);
    l23 = __builtin_amdgcn_perm(au(r3), au(r2), 0x07060302);
}

#define MFMA(a,b,c) __builtin_amdgcn_mfma_f32_16x16x32_bf16((a),(b),(c),0,0,0)

__global__ __launch_bounds__(256, 2) void bigbird_attn(
    const float* __restrict__ Qg, const float* __restrict__ Kg, const float* __restrict__ Vg,
    const float* __restrict__ band_mask, const float* __restrict__ from_mask,
    const float* __restrict__ to_mask, const float* __restrict__ fbm,
    const float* __restrict__ tbm, const int* __restrict__ rand_attn,
    float* __restrict__ out, float* __restrict__ ws)
{
    const int H = 12, S = 4096;
    __shared__ __align__(16) unsigned short lds[LDS_TOT];

    const int tid  = threadIdx.x;
    const int w    = tid >> 6;        // wave 0..3 -> q rows [16w,16w+16)
    const int lane = tid & 63;
    const int l15  = lane & 15;
    const int l4   = lane >> 4;       // 0..3

    int wg = blockIdx.x;
    int b, h, m, seg = 0;
    bool partial;
    if (wg < 384) {                   // full rows (m=0,63) split into 8 segments
        partial = true;
        b = wg / 192;
        int r = wg - b*192;
        h = r >> 4;
        int r2 = r & 15;
        m = (r2 >> 3) ? 63 : 0;
        seg = r2 & 7;
    } else {
        partial = false;
        int ww = wg - 384;
        b = ww / (H*62);
        int r = ww - b*H*62;
        h = r / 62;
        m = 1 + (r - h*62);
    }

    const long bh = (long)b*H + h;
    const float* Qb = Qg + (bh*S + (long)m*64)*64;
    const float* Kb = Kg + bh*S*64;
    const float* Vb = Vg + bh*S*64;

    const bool isMid = (m >= 2) && (m <= 61);
    int nt_cnt;
    int r0 = 1, r1 = 1, r2i = 1;
    if (partial) nt_cnt = 8;
    else {
        const int* ra = rand_attn + (bh*62 + (m-1))*3;
        r0 = ra[0]; r1 = ra[1]; r2i = ra[2];
        nt_cnt = isMid ? 8 : 7;
    }

    // ---- stage Q (hi/lo bf16), rows 0..63 ----
    #pragma unroll
    for (int c = 0; c < 4; ++c) {
        int s = tid + 256*c;
        int row = s >> 4, d4 = (s & 15) << 2;
        float4 qv = *(const float4*)&Qb[row*64 + d4];
        unsigned h01,h23,l01,l23; pack4(qv.x,qv.y,qv.z,qv.w,h01,h23,l01,l23);
        *(uint2*)&lds[QH + row*LROW + d4] = make_uint2(h01,h23);
        *(uint2*)&lds[QL + row*LROW + d4] = make_uint2(l01,l23);
    }

    f32x4 oacc[4];
    float mrow[4], lrow[4];
    #pragma unroll
    for (int i = 0; i < 4; ++i) {
        oacc[i] = (f32x4){0.f,0.f,0.f,0.f};
        mrow[i] = -INFINITY; lrow[i] = 0.f;
    }

    for (int t = 0; t < nt_cnt; ++t) {
        int blk, ty;   // ty: 0=to_mask 1..3=window 4=rand
        if (partial)     { blk = seg*8 + t; ty = 0; }
        else if (isMid) {
            if (t == 0)      { blk = 0;       ty = 0; }
            else if (t <= 3) { blk = m-2 + t; ty = t; }
            else if (t <= 6) { blk = (t==4)?r0:((t==5)?r1:r2i); ty = 4; }
            else             { blk = 63;      ty = 0; }
        } else {
            if (t < 4) { blk = (m==1) ? ((t<3)? t : 63) : ((t==0)? 0 : 60+t); ty = 0; }
            else       { blk = (t==4)?r0:((t==5)?r1:r2i); ty = 4; }
        }

        __syncthreads();   // prev tile's MFMAs done reading K/V

        // ---- stage K rows (hi/lo) ----
        {
            const float* Kt = Kb + (long)blk*4096;
            #pragma unroll
            for (int c = 0; c < 4; ++c) {
                int s = tid + 256*c;
                int row = s >> 4, d4 = (s & 15) << 2;
                float4 kv = *(const float4*)&Kt[row*64 + d4];
                unsigned h01,h23,l01,l23; pack4(kv.x,kv.y,kv.z,kv.w,h01,h23,l01,l23);
                *(uint2*)&lds[KH + row*LROW + d4] = make_uint2(h01,h23);
                *(uint2*)&lds[KL + row*LROW + d4] = make_uint2(l01,l23);
            }
        }
        // ---- stage V transposed: Vt[d][key] (hi/lo) ----
        {
            const float* Vt0 = Vb + (long)blk*4096;
            int d  = tid & 63;
            int kg = tid >> 6;          // = wave id; keys kg*4..kg*4+3 per pass
            #pragma unroll
            for (int p = 0; p < 4; ++p) {
                int k0 = p*16 + kg*4;
                float x0 = Vt0[(k0+0)*64 + d];
                float x1 = Vt0[(k0+1)*64 + d];
                float x2 = Vt0[(k0+2)*64 + d];
                float x3 = Vt0[(k0+3)*64 + d];
                unsigned h01,h23,l01,l23; pack4(x0,x1,x2,x3,h01,h23,l01,l23);
                *(uint2*)&lds[VTH + d*LROW + k0] = make_uint2(h01,h23);
                *(uint2*)&lds[VTL + d*LROW + k0] = make_uint2(l01,l23);
            }
        }
        __syncthreads();   // staging visible

        // ---- QK^T via MFMA: 4 key-ntiles, 2 d-ksteps, 3 split terms ----
        f32x4 sacc[4];
        #pragma unroll
        for (int nt = 0; nt < 4; ++nt) sacc[nt] = (f32x4){0.f,0.f,0.f,0.f};
        #pragma unroll
        for (int ks = 0; ks < 2; ++ks) {
            int col = l4*8 + 32*ks;
            short8v qh = *(const short8v*)&lds[QH + (16*w + l15)*LROW + col];
            short8v ql = *(const short8v*)&lds[QL + (16*w + l15)*LROW + col];
            #pragma unroll
            for (int nt = 0; nt < 4; ++nt) {
                short8v kh = *(const short8v*)&lds[KH + (nt*16 + l15)*LROW + col];
                short8v kl = *(const short8v*)&lds[KL + (nt*16 + l15)*LROW + col];
                sacc[nt] = MFMA(qh, kh, sacc[nt]);
                sacc[nt] = MFMA(qh, kl, sacc[nt]);
                sacc[nt] = MFMA(ql, kh, sacc[nt]);
            }
        }

        // ---- mask precompute (lane-dependent parts) ----
        float ak[4], tb[4];
        const float* bmb = nullptr;
        if (ty == 0) {
            #pragma unroll
            for (int nt = 0; nt < 4; ++nt)
                ak[nt] = (1.f - to_mask[(long)b*S + blk*64 + nt*16 + l15]) * -10000.f;
        } else if (ty <= 3) {
            bmb = band_mask + ((long)(b*60 + (m-2)))*64*192 + (ty-1)*64;
        } else {
            #pragma unroll
            for (int nt = 0; nt < 4; ++nt)
                tb[nt] = tbm[((long)b*64 + blk)*64 + nt*16 + l15];
        }

        // ---- online softmax (C layout: col=key=l15+16nt, row=q=l4*4+reg) ----
        f32x4 alv;
        #pragma unroll
        for (int reg = 0; reg < 4; ++reg) {
            int qb = 16*w + l4*4 + reg;       // q row within 64-block
            float fq = (ty == 4) ? fbm[((long)b*64 + m)*64 + qb] : 0.f;
            float sc[4];
            #pragma unroll
            for (int nt = 0; nt < 4; ++nt) {
                float addend;
                if (ty == 0)      addend = ak[nt];
                else if (ty <= 3) addend = (1.f - bmb[qb*192 + nt*16 + l15]) * -10000.f;
                else              addend = (1.f - fq*tb[nt]) * -10000.f;
                sc[nt] = sacc[nt][reg]*0.125f + addend;
            }
            float mx = fmaxf(fmaxf(sc[0],sc[1]), fmaxf(sc[2],sc[3]));
            mx = fmaxf(mx, __shfl_xor(mx, 1));
            mx = fmaxf(mx, __shfl_xor(mx, 2));
            mx = fmaxf(mx, __shfl_xor(mx, 4));
            mx = fmaxf(mx, __shfl_xor(mx, 8));
            float mn = fmaxf(mrow[reg], mx);
            float al = __expf(mrow[reg] - mn);
            float p0 = __expf(sc[0] - mn);
            float p1 = __expf(sc[1] - mn);
            float p2 = __expf(sc[2] - mn);
            float p3 = __expf(sc[3] - mn);
            float ls = p0 + p1 + p2 + p3;
            ls += __shfl_xor(ls, 1);
            ls += __shfl_xor(ls, 2);
            ls += __shfl_xor(ls, 4);
            ls += __shfl_xor(ls, 8);
            lrow[reg] = lrow[reg]*al + ls;
            mrow[reg] = mn;
            alv[reg] = al;
            // write P hi/lo (row qb is private to this wave: qb in [16w,16w+16))
            float pv[4] = {p0,p1,p2,p3};
            #pragma unroll
            for (int nt = 0; nt < 4; ++nt) {
                unsigned up = au(pv[nt]);
                unsigned short phi = (unsigned short)(up >> 16);
                float rlo = pv[nt] - af(up & 0xffff0000u);
                unsigned short plo = (unsigned short)(au(rlo) >> 16);
                lds[PHO + qb*LROW + nt*16 + l15] = phi;
                lds[PLO + qb*LROW + nt*16 + l15] = plo;
            }
        }

        // P writes are read back cross-lane within this wave: drain LDS queue
        asm volatile("s_waitcnt lgkmcnt(0)" ::: "memory");

        // ---- rescale running output, then PV via MFMA ----
        #pragma unroll
        for (int dnt = 0; dnt < 4; ++dnt) oacc[dnt] *= alv;
        #pragma unroll
        for (int ks = 0; ks < 2; ++ks) {
            int col = l4*8 + 32*ks;
            short8v ph = *(const short8v*)&lds[PHO + (16*w + l15)*LROW + col];
            short8v pl = *(const short8v*)&lds[PLO + (16*w + l15)*LROW + col];
            #pragma unroll
            for (int dnt = 0; dnt < 4; ++dnt) {
                short8v vh = *(const short8v*)&lds[VTH + (dnt*16 + l15)*LROW + col];
                short8v vl = *(const short8v*)&lds[VTL + (dnt*16 + l15)*LROW + col];
                oacc[dnt] = MFMA(ph, vh, oacc[dnt]);
                oacc[dnt] = MFMA(ph, vl, oacc[dnt]);
                oacc[dnt] = MFMA(pl, vh, oacc[dnt]);
            }
        }
    }

    // ---- epilogue ----
    if (partial) {
        float* P = ws + ((bh*2 + (m ? 1 : 0))*8 + seg) * PS;
        #pragma unroll
        for (int reg = 0; reg < 4; ++reg) {
            int qb = 16*w + l4*4 + reg;
            #pragma unroll
            for (int dnt = 0; dnt < 4; ++dnt)
                P[qb*64 + dnt*16 + l15] = oacc[dnt][reg];
            if (l15 == 0) { P[4096 + qb] = mrow[reg]; P[4160 + qb] = lrow[reg]; }
        }
    } else {
        #pragma unroll
        for (int reg = 0; reg < 4; ++reg) {
            int qg = m*64 + 16*w + l4*4 + reg;
            float scn = (1.f / lrow[reg]) * from_mask[(long)b*S + qg];
            #pragma unroll
            for (int dnt = 0; dnt < 4; ++dnt)
                out[((long)((long)b*S + qg)*H + h)*64 + dnt*16 + l15] = oacc[dnt][reg] * scn;
        }
    }
}

__global__ __launch_bounds__(256) void bigbird_reduce(
    const float* __restrict__ ws, const float* __restrict__ from_mask,
    float* __restrict__ out)
{
    const int H = 12, S = 4096;
    int rowIdx = blockIdx.x;                 // 0..47 = (b*H + h)*2 + mi
    int b  = rowIdx / 24;
    int r  = rowIdx - b*24;
    int h  = r >> 1;
    int mi = r & 1;
    int m  = mi ? 63 : 0;

    const float* base = ws + (long)rowIdx * 8 * PS;
    int tid = threadIdx.x;
    int q  = tid >> 2;
    int dd = (tid & 3) << 4;

    float msg[8], lsg[8];
    float M = -INFINITY;
    #pragma unroll
    for (int s = 0; s < 8; ++s) {
        msg[s] = base[s*PS + 4096 + q];
        lsg[s] = base[s*PS + 4160 + q];
        M = fmaxf(M, msg[s]);
    }
    float L = 0.f, wv[8];
    #pragma unroll
    for (int s = 0; s < 8; ++s) { wv[s] = __expf(msg[s] - M); L += wv[s]*lsg[s]; }

    int qg = m*64 + q;
    float sc = from_mask[(long)b*S + qg] / L;

    #pragma unroll
    for (int c = 0; c < 4; ++c) {
        float4 o = make_float4(0.f, 0.f, 0.f, 0.f);
        #pragma unroll
        for (int s = 0; s < 8; ++s) {
            float4 a = *(const float4*)&base[s*PS + q*64 + dd + 4*c];
            o.x += wv[s]*a.x; o.y += wv[s]*a.y; o.z += wv[s]*a.z; o.w += wv[s]*a.w;
        }
        o.x *= sc; o.y *= sc; o.z *= sc; o.w *= sc;
        *(float4*)&out[((long)((long)b*S + qg)*H + h)*64 + dd + 4*c] = o;
    }
}

extern "C" void kernel_launch(void* const* d_in, const int* in_sizes, int n_in,
                              void* d_out, int out_size, void* d_ws, size_t ws_size,
                              hipStream_t stream) {
    const float* q   = (const float*)d_in[0];
    const float* k   = (const float*)d_in[1];
    const float* v   = (const float*)d_in[2];
    const float* bm  = (const float*)d_in[3];
    const float* fm  = (const float*)d_in[4];
    const float* tm  = (const float*)d_in[5];
    const float* fbm = (const float*)d_in[6];
    const float* tbm = (const float*)d_in[7];
    const int*   ra  = (const int*)d_in[8];
    float* out = (float*)d_out;
    float* ws  = (float*)d_ws;   // 48 rows * 8 segs * 4224 floats = 6.5 MB

    bigbird_attn<<<dim3(384 + 2*12*62), dim3(256), 0, stream>>>(q, k, v, bm, fm, tm, fbm, tbm, ra, out, ws);
    bigbird_reduce<<<dim3(48), dim3(256), 0, stream>>>(ws, fm, out);
}

// Round 8
// 201.505 us; speedup vs baseline: 2.8754x; 1.3583x over previous
//
#include <hip/hip_runtime.h>
#include <math.h>

#define PS 4224          // partial stride (floats): 64*64 acc + 64 m + 64 l
#define NEG -10000.f

typedef short short8v __attribute__((ext_vector_type(8)));
typedef float f32x4  __attribute__((ext_vector_type(4)));

// LDS: 4 regions, 64 rows x 64 ushorts (128B rows, XOR-swizzled 16B slots)
#define KHo  0
#define KLo  4096
#define VTHo 8192
#define VTLo 12288
#define LDS_TOT 16384    // ushorts = 32 KB -> LDS allows 5 WG/CU; VGPR bound ~3

__device__ __forceinline__ unsigned au(float x){ return __float_as_uint(x); }
__device__ __forceinline__ float    af(unsigned x){ return __uint_as_float(x); }

// split 4 floats into packed-bf16 hi pair-words and lo pair-words (truncate; lo compensates)
__device__ __forceinline__ void pack4(float a, float b, float c, float d,
                                      unsigned &h01, unsigned &h23,
                                      unsigned &l01, unsigned &l23) {
    unsigned u0=au(a), u1=au(b), u2=au(c), u3=au(d);
    h01 = __builtin_amdgcn_perm(u1, u0, 0x07060302);   // [bf16(b) | bf16(a)]
    h23 = __builtin_amdgcn_perm(u3, u2, 0x07060302);
    float r0 = a - af(u0 & 0xffff0000u);
    float r1 = b - af(u1 & 0xffff0000u);
    float r2 = c - af(u2 & 0xffff0000u);
    float r3 = d - af(u3 & 0xffff0000u);
    l01 = __builtin_amdgcn_perm(au(r1), au(r0), 0x07060302);
    l23 = __builtin_amdgcn_perm(au(r3), au(r2), 0x07060302);
}

// ushort index into a 64x64 region with XOR-swizzled 16B slots: conflict-free
// b128 frag reads (lanes: row=l15-varying, slot fixed) and ~free staging writes.
__device__ __forceinline__ int swz(int row, int colus) {
    return row*64 + (((colus>>3) ^ (row&7))<<3) + (colus&7);
}

#define MFMA(a,b,c) __builtin_amdgcn_mfma_f32_16x16x32_bf16((a),(b),(c),0,0,0)

union FragU { unsigned u[4]; short8v s; };

__device__ __forceinline__ void tile_of(bool partial, bool isMid, int m, int seg,
                                        int r0, int r1, int r2i, int t,
                                        int &blk, int &ty) {
    if (partial)     { blk = seg*8 + t; ty = 0; }
    else if (isMid) {
        if (t == 0)      { blk = 0;       ty = 0; }
        else if (t <= 3) { blk = m-2 + t; ty = t; }
        else if (t <= 6) { blk = (t==4)?r0:((t==5)?r1:r2i); ty = 4; }
        else             { blk = 63;      ty = 0; }
    } else {
        if (t < 4) { blk = (m==1) ? ((t<3)? t : 63) : ((t==0)? 0 : 60+t); ty = 0; }
        else       { blk = (t==4)?r0:((t==5)?r1:r2i); ty = 4; }
    }
}

__global__ __launch_bounds__(256, 3) void bigbird_attn(
    const float* __restrict__ Qg, const float* __restrict__ Kg, const float* __restrict__ Vg,
    const float* __restrict__ band_mask, const float* __restrict__ from_mask,
    const float* __restrict__ to_mask, const float* __restrict__ fbm,
    const float* __restrict__ tbm, const int* __restrict__ rand_attn,
    float* __restrict__ out, float* __restrict__ ws)
{
    const int H = 12, S = 4096;
    __shared__ __align__(16) unsigned short lds[LDS_TOT];

    const int tid  = threadIdx.x;
    const int w    = tid >> 6;        // wave 0..3 -> q rows [16w,16w+16)
    const int lane = tid & 63;
    const int l15  = lane & 15;       // q-row offset (B-frag), LDS frag row offset
    const int l4   = lane >> 4;       // 0..3: k-slice / C-row quad

    int wg = blockIdx.x;
    int b, h, m, seg = 0;
    bool partial;
    if (wg < 384) {                   // full rows (m=0,63) split into 8 segments
        partial = true;
        b = wg / 192;
        int r = wg - b*192;
        h = r >> 4;
        int r2 = r & 15;
        m = (r2 >> 3) ? 63 : 0;
        seg = r2 & 7;
    } else {
        partial = false;
        int ww = wg - 384;
        b = ww / (H*62);
        int r = ww - b*H*62;
        h = r / 62;
        m = 1 + (r - h*62);
    }

    const long bh = (long)b*H + h;
    const float* Qb = Qg + (bh*S + (long)m*64)*64;
    const float* Kb = Kg + bh*S*64;
    const float* Vb = Vg + bh*S*64;

    const bool isMid = (m >= 2) && (m <= 61);
    int nt_cnt;
    int r0 = 1, r1 = 1, r2i = 1;
    if (partial) nt_cnt = 8;
    else {
        const int* ra = rand_attn + (bh*62 + (m-1))*3;
        r0 = ra[0]; r1 = ra[1]; r2i = ra[2];
        nt_cnt = isMid ? 8 : 7;
    }

    // ---- Q fragments straight to registers (B-operand; no LDS) ----
    short8v qhf[2], qlf[2];
    #pragma unroll
    for (int ks = 0; ks < 2; ++ks) {
        const float* qp = &Qb[(16*w + l15)*64 + l4*8 + 32*ks];
        float4 a = *(const float4*)qp;
        float4 b2 = *(const float4*)(qp + 4);
        FragU fh, fl;
        pack4(a.x,a.y,a.z,a.w, fh.u[0],fh.u[1], fl.u[0],fl.u[1]);
        pack4(b2.x,b2.y,b2.z,b2.w, fh.u[2],fh.u[3], fl.u[2],fl.u[3]);
        qhf[ks] = fh.s; qlf[ks] = fl.s;
    }

    // staging thread mapping
    const int kr0 = tid >> 4;          // K rows kr0 + 16c
    const int kc  = (tid & 15) << 2;   // K col (floats/ushorts)
    const int vd  = tid & 63;          // V: d row
    const int vkg = tid >> 6;          // V: key group

    // ---- prefetch tile 0 ----
    int blkN, tyN;
    tile_of(partial, isMid, m, seg, r0, r1, r2i, 0, blkN, tyN);
    float4 kreg[4];
    float  vreg[16];
    {
        const float* Kt = Kb + (long)blkN*4096;
        const float* Vt0 = Vb + (long)blkN*4096;
        #pragma unroll
        for (int c = 0; c < 4; ++c) kreg[c] = *(const float4*)&Kt[(kr0+16*c)*64 + kc];
        #pragma unroll
        for (int p = 0; p < 4; ++p)
            #pragma unroll
            for (int i = 0; i < 4; ++i)
                vreg[p*4+i] = Vt0[(p*16 + vkg*4 + i)*64 + vd];
    }

    f32x4 oacc[4];
    #pragma unroll
    for (int i = 0; i < 4; ++i) oacc[i] = (f32x4){0.f,0.f,0.f,0.f};
    float mrow = -INFINITY, lrow = 0.f;

    for (int t = 0; t < nt_cnt; ++t) {
        const int blk = blkN, ty = tyN;

        __syncthreads();   // prev tile's MFMAs done reading LDS

        // ---- stage K (rows) and V^T (keys along rows of d) from regs ----
        #pragma unroll
        for (int c = 0; c < 4; ++c) {
            FragU fh, fl;
            pack4(kreg[c].x,kreg[c].y,kreg[c].z,kreg[c].w, fh.u[0],fh.u[1], fl.u[0],fl.u[1]);
            int o = swz(kr0+16*c, kc);
            *(uint2*)&lds[KHo + o] = make_uint2(fh.u[0],fh.u[1]);
            *(uint2*)&lds[KLo + o] = make_uint2(fl.u[0],fl.u[1]);
        }
        #pragma unroll
        for (int p = 0; p < 4; ++p) {
            FragU fh, fl;
            pack4(vreg[p*4+0],vreg[p*4+1],vreg[p*4+2],vreg[p*4+3],
                  fh.u[0],fh.u[1], fl.u[0],fl.u[1]);
            int o = swz(vd, p*16 + vkg*4);
            *(uint2*)&lds[VTHo + o] = make_uint2(fh.u[0],fh.u[1]);
            *(uint2*)&lds[VTLo + o] = make_uint2(fl.u[0],fl.u[1]);
        }
        __syncthreads();   // staging visible

        // ---- prefetch next tile into regs (latency hides under compute) ----
        if (t + 1 < nt_cnt) {
            tile_of(partial, isMid, m, seg, r0, r1, r2i, t+1, blkN, tyN);
            const float* Kt = Kb + (long)blkN*4096;
            const float* Vt0 = Vb + (long)blkN*4096;
            #pragma unroll
            for (int c = 0; c < 4; ++c) kreg[c] = *(const float4*)&Kt[(kr0+16*c)*64 + kc];
            #pragma unroll
            for (int p = 0; p < 4; ++p)
                #pragma unroll
                for (int i = 0; i < 4; ++i)
                    vreg[p*4+i] = Vt0[(p*16 + vkg*4 + i)*64 + vd];
        }

        // ---- mask addend (vectorized; key = 16nt + 4*l4 + reg, q = 16w + l15) ----
        f32x4 addv[4];
        if (ty == 0) {
            #pragma unroll
            for (int nt = 0; nt < 4; ++nt) {
                f32x4 tv = *(const f32x4*)&to_mask[(long)b*S + blk*64 + 16*nt + 4*l4];
                addv[nt] = (1.f - tv) * NEG;
            }
        } else if (ty <= 3) {
            const float* bq = band_mask + ((long)(b*60 + (m-2)))*64*192
                              + (16*w + l15)*192 + (ty-1)*64;
            #pragma unroll
            for (int nt = 0; nt < 4; ++nt) {
                f32x4 tv = *(const f32x4*)&bq[16*nt + 4*l4];
                addv[nt] = (1.f - tv) * NEG;
            }
        } else {
            float fq = fbm[((long)b*64 + m)*64 + 16*w + l15];
            #pragma unroll
            for (int nt = 0; nt < 4; ++nt) {
                f32x4 tv = *(const f32x4*)&tbm[((long)b*64 + blk)*64 + 16*nt + 4*l4];
                addv[nt] = (1.f - fq*tv) * NEG;
            }
        }

        // ---- QK^T swapped: S^T[key][q]; lane holds 16 scores of ONE q row ----
        f32x4 sacc[4];
        #pragma unroll
        for (int nt = 0; nt < 4; ++nt) sacc[nt] = (f32x4){0.f,0.f,0.f,0.f};
        #pragma unroll
        for (int ks = 0; ks < 2; ++ks) {
            const int col = l4*8 + 32*ks;
            #pragma unroll
            for (int nt = 0; nt < 4; ++nt) {
                int o = swz(16*nt + l15, col);
                short8v kh = *(const short8v*)&lds[KHo + o];
                short8v kl = *(const short8v*)&lds[KLo + o];
                sacc[nt] = MFMA(kh, qhf[ks], sacc[nt]);
                sacc[nt] = MFMA(kl, qhf[ks], sacc[nt]);
                sacc[nt] = MFMA(kh, qlf[ks], sacc[nt]);
            }
        }

        // ---- online softmax: reduce over own 16 + l4-group (xor 16,32) ----
        f32x4 sr[4];
        float mx = -INFINITY;
        #pragma unroll
        for (int nt = 0; nt < 4; ++nt) {
            sr[nt] = sacc[nt]*0.125f + addv[nt];
            mx = fmaxf(mx, fmaxf(fmaxf(sr[nt][0], sr[nt][1]), fmaxf(sr[nt][2], sr[nt][3])));
        }
        mx = fmaxf(mx, __shfl_xor(mx, 16));
        mx = fmaxf(mx, __shfl_xor(mx, 32));
        float mn = fmaxf(mrow, mx);
        float al = __expf(mrow - mn);
        float ls = 0.f;
        f32x4 pq[4];
        #pragma unroll
        for (int nt = 0; nt < 4; ++nt) {
            pq[nt][0] = __expf(sr[nt][0] - mn);
            pq[nt][1] = __expf(sr[nt][1] - mn);
            pq[nt][2] = __expf(sr[nt][2] - mn);
            pq[nt][3] = __expf(sr[nt][3] - mn);
            ls += pq[nt][0] + pq[nt][1] + pq[nt][2] + pq[nt][3];
        }
        ls += __shfl_xor(ls, 16);
        ls += __shfl_xor(ls, 32);
        lrow = lrow*al + ls;
        mrow = mn;

        // ---- pack P quads to bf16 hi/lo (in regs) ----
        unsigned ph01[4], ph23[4], pl01[4], pl23[4];
        #pragma unroll
        for (int nt = 0; nt < 4; ++nt)
            pack4(pq[nt][0],pq[nt][1],pq[nt][2],pq[nt][3],
                  ph01[nt],ph23[nt], pl01[nt],pl23[nt]);

        // ---- redistribute P^T -> PV B-frag via shfl_xor within l4-group ----
        // lane l4 needs quads (nt=(l4>>1)+2ks) from src lanes 2(l4&1), 2(l4&1)+1
        short8v pbh[2], pbl[2];
        #pragma unroll
        for (int ks = 0; ks < 2; ++ks) {
            const int loNT = 2*ks, hiNT = 2*ks+1;
            const bool up = (l4 & 2);
            unsigned aH0 = up ? ph01[hiNT] : ph01[loNT];
            unsigned aH1 = up ? ph23[hiNT] : ph23[loNT];
            unsigned aL0 = up ? pl01[hiNT] : pl01[loNT];
            unsigned aL1 = up ? pl23[hiNT] : pl23[loNT];
            unsigned sH0 = up ? ph01[loNT] : ph01[hiNT];
            unsigned sH1 = up ? ph23[loNT] : ph23[hiNT];
            unsigned sL0 = up ? pl01[loNT] : pl01[hiNT];
            unsigned sL1 = up ? pl23[loNT] : pl23[hiNT];
            unsigned x16H0 = __shfl_xor((int)aH0, 16), x16H1 = __shfl_xor((int)aH1, 16);
            unsigned x16L0 = __shfl_xor((int)aL0, 16), x16L1 = __shfl_xor((int)aL1, 16);
            unsigned x32H0 = __shfl_xor((int)sH0, 32), x32H1 = __shfl_xor((int)sH1, 32);
            unsigned x32L0 = __shfl_xor((int)sL0, 32), x32L1 = __shfl_xor((int)sL1, 32);
            unsigned x48H0 = __shfl_xor((int)sH0, 48), x48H1 = __shfl_xor((int)sH1, 48);
            unsigned x48L0 = __shfl_xor((int)sL0, 48), x48L1 = __shfl_xor((int)sL1, 48);
            FragU fh, fl;
            fh.u[0] = (l4==0)?aH0 : (l4==1)?x48H0 : (l4==2)?x32H0 : x16H0;
            fh.u[1] = (l4==0)?aH1 : (l4==1)?x48H1 : (l4==2)?x32H1 : x16H1;
            fh.u[2] = (l4==0)?x16H0 : (l4==1)?x32H0 : (l4==2)?x48H0 : aH0;
            fh.u[3] = (l4==0)?x16H1 : (l4==1)?x32H1 : (l4==2)?x48H1 : aH1;
            fl.u[0] = (l4==0)?aL0 : (l4==1)?x48L0 : (l4==2)?x32L0 : x16L0;
            fl.u[1] = (l4==0)?aL1 : (l4==1)?x48L1 : (l4==2)?x32L1 : x16L1;
            fl.u[2] = (l4==0)?x16L0 : (l4==1)?x32L0 : (l4==2)?x48L0 : aL0;
            fl.u[3] = (l4==0)?x16L1 : (l4==1)?x32L1 : (l4==2)?x48L1 : aL1;
            pbh[ks] = fh.s; pbl[ks] = fl.s;
        }

        // ---- rescale, then PV: O^T[d][q] = Vt x P ----
        #pragma unroll
        for (int dnt = 0; dnt < 4; ++dnt) oacc[dnt] *= al;
        #pragma unroll
        for (int ks = 0; ks < 2; ++ks) {
            const int col = l4*8 + 32*ks;
            #pragma unroll
            for (int dnt = 0; dnt < 4; ++dnt) {
                int o = swz(16*dnt + l15, col);
                short8v vh = *(const short8v*)&lds[VTHo + o];
                short8v vl = *(const short8v*)&lds[VTLo + o];
                oacc[dnt] = MFMA(vh, pbh[ks], oacc[dnt]);
                oacc[dnt] = MFMA(vl, pbh[ks], oacc[dnt]);
                oacc[dnt] = MFMA(vh, pbl[ks], oacc[dnt]);
            }
        }
    }

    // ---- epilogue: lane owns q = 16w + l15, d = 16dnt + 4*l4 + 0..3 ----
    const int q64 = 16*w + l15;
    if (partial) {
        float* P = ws + ((bh*2 + (m ? 1 : 0))*8 + seg) * PS;
        #pragma unroll
        for (int dnt = 0; dnt < 4; ++dnt)
            *(f32x4*)&P[q64*64 + 16*dnt + 4*l4] = oacc[dnt];
        if (l4 == 0) { P[4096 + q64] = mrow; P[4160 + q64] = lrow; }
    } else {
        int qg = m*64 + q64;
        float scn = (1.f / lrow) * from_mask[(long)b*S + qg];
        #pragma unroll
        for (int dnt = 0; dnt < 4; ++dnt) {
            f32x4 o = oacc[dnt] * scn;
            *(f32x4*)&out[((long)((long)b*S + qg)*H + h)*64 + 16*dnt + 4*l4] = o;
        }
    }
}

__global__ __launch_bounds__(256) void bigbird_reduce(
    const float* __restrict__ ws, const float* __restrict__ from_mask,
    float* __restrict__ out)
{
    const int H = 12, S = 4096;
    int rowIdx = blockIdx.x;                 // 0..47 = (b*H + h)*2 + mi
    int b  = rowIdx / 24;
    int r  = rowIdx - b*24;
    int h  = r >> 1;
    int mi = r & 1;
    int m  = mi ? 63 : 0;

    const float* base = ws + (long)rowIdx * 8 * PS;
    int tid = threadIdx.x;
    int q  = tid >> 2;
    int dd = (tid & 3) << 4;

    float msg[8], lsg[8];
    float M = -INFINITY;
    #pragma unroll
    for (int s = 0; s < 8; ++s) {
        msg[s] = base[s*PS + 4096 + q];
        lsg[s] = base[s*PS + 4160 + q];
        M = fmaxf(M, msg[s]);
    }
    float L = 0.f, wv[8];
    #pragma unroll
    for (int s = 0; s < 8; ++s) { wv[s] = __expf(msg[s] - M); L += wv[s]*lsg[s]; }

    int qg = m*64 + q;
    float sc = from_mask[(long)b*S + qg] / L;

    #pragma unroll
    for (int c = 0; c < 4; ++c) {
        float4 o = make_float4(0.f, 0.f, 0.f, 0.f);
        #pragma unroll
        for (int s = 0; s < 8; ++s) {
            float4 a = *(const float4*)&base[s*PS + q*64 + dd + 4*c];
            o.x += wv[s]*a.x; o.y += wv[s]*a.y; o.z += wv[s]*a.z; o.w += wv[s]*a.w;
        }
        o.x *= sc; o.y *= sc; o.z *= sc; o.w *= sc;
        *(float4*)&out[((long)((long)b*S + qg)*H + h)*64 + dd + 4*c] = o;
    }
}

extern "C" void kernel_launch(void* const* d_in, const int* in_sizes, int n_in,
                              void* d_out, int out_size, void* d_ws, size_t ws_size,
                              hipStream_t stream) {
    const float* q   = (const float*)d_in[0];
    const float* k   = (const float*)d_in[1];
    const float* v   = (const float*)d_in[2];
    const float* bm  = (const float*)d_in[3];
    const float* fm  = (const float*)d_in[4];
    const float* tm  = (const float*)d_in[5];
    const float* fbm = (const float*)d_in[6];
    const float* tbm = (const float*)d_in[7];
    const int*   ra  = (const int*)d_in[8];
    float* out = (float*)d_out;
    float* ws  = (float*)d_ws;   // 48 rows * 8 segs * 4224 floats = 6.5 MB

    bigbird_attn<<<dim3(384 + 2*12*62), dim3(256), 0, stream>>>(q, k, v, bm, fm, tm, fbm, tbm, ra, out, ws);
    bigbird_reduce<<<dim3(48), dim3(256), 0, stream>>>(ws, fm, out);
}